// Round 3
// baseline (337.216 us; speedup 1.0000x reference)
//
#include <hip/hip_runtime.h>

// ---- types ----
typedef short bf16x8 __attribute__((ext_vector_type(8)));
typedef float f32x4 __attribute__((ext_vector_type(4)));

__device__ __forceinline__ unsigned short f2bf(float f) {
  unsigned u = __builtin_bit_cast(unsigned, f);
  u += 0x7fff + ((u >> 16) & 1);   // RNE
  return (unsigned short)(u >> 16);
}

__device__ __forceinline__ void gload_lds16(const void* g, void* l) {
  __builtin_amdgcn_global_load_lds(
      (const __attribute__((address_space(1))) void*)g,
      (__attribute__((address_space(3))) void*)l, 16, 0, 0);
}

// ---- fp32 -> bf16 elementwise (vectorized float4 -> ushort4) ----
__global__ __launch_bounds__(256) void cvt_f32_bf16(const float* __restrict__ in,
                                                    unsigned short* __restrict__ out,
                                                    int n4) {
  int i = blockIdx.x * blockDim.x + threadIdx.x;
  int stride = gridDim.x * blockDim.x;
  for (; i < n4; i += stride) {
    float4 v = ((const float4*)in)[i];
    ushort4 o;
    o.x = f2bf(v.x); o.y = f2bf(v.y); o.z = f2bf(v.z); o.w = f2bf(v.w);
    ((ushort4*)out)[i] = o;
  }
}

// ---- transpose + convert: in [R][C] f32 -> out [C][R] bf16 ----
__global__ __launch_bounds__(256) void tconv(const float* __restrict__ in,
                                             unsigned short* __restrict__ out,
                                             int R, int C) {
  __shared__ float tile[32][33];
  const int c0 = blockIdx.x * 32, r0 = blockIdx.y * 32;
  const int tid = threadIdx.x;
  const int tr = tid >> 3;        // 0..31
  const int tc4 = tid & 7;        // 0..7, 4 floats each
  float4 v = *(const float4*)&in[(size_t)(r0 + tr) * C + c0 + tc4 * 4];
  tile[tr][tc4 * 4 + 0] = v.x;
  tile[tr][tc4 * 4 + 1] = v.y;
  tile[tr][tc4 * 4 + 2] = v.z;
  tile[tr][tc4 * 4 + 3] = v.w;
  __syncthreads();
#pragma unroll
  for (int i = 0; i < 4; ++i)
    out[(size_t)(c0 + tr) * R + r0 + tc4 * 4 + i] = f2bf(tile[tc4 * 4 + i][tr]);
}

// ---- bf16 MFMA GEMM: C[M][N] = A[M][K] * B^T[N][K] ----
// 128x128 tile, BK=64, 4 waves (2x2), each wave 64x64 out.
template <int OUT_BF16>
__global__ __launch_bounds__(256) void gemm_bt(const unsigned short* __restrict__ A,
                                               const unsigned short* __restrict__ B,
                                               void* __restrict__ Cv,
                                               int M, int N, int K) {
  __shared__ unsigned short As[128 * 64];
  __shared__ unsigned short Bs[128 * 64];
  const int tid = threadIdx.x;
  const int wv = tid >> 6, lane = tid & 63;
  const int l15 = lane & 15, lg = lane >> 4;
  const int bm = blockIdx.y, bn = blockIdx.x;
  const int wr = wv >> 1, wc = wv & 1;
  f32x4 acc[4][4] = {};
  const unsigned short* Ab = A + (size_t)bm * 128 * K;
  const unsigned short* Bb = B + (size_t)bn * 128 * K;

  for (int k0 = 0; k0 < K; k0 += 64) {
#pragma unroll
    for (int i = 0; i < 4; ++i) {
      int s = i * 256 + wv * 64 + lane;
      int row = s >> 3, pc = s & 7;
      int lc = pc ^ (row & 7);      // source pre-swizzle; LDS dest stays linear
      gload_lds16(Ab + (size_t)row * K + k0 + lc * 8,
                  (char*)As + (size_t)(i * 256 + wv * 64) * 16);
      gload_lds16(Bb + (size_t)row * K + k0 + lc * 8,
                  (char*)Bs + (size_t)(i * 256 + wv * 64) * 16);
    }
    __syncthreads();
#pragma unroll
    for (int kh = 0; kh < 2; ++kh) {
      bf16x8 af[4], bf[4];
#pragma unroll
      for (int m = 0; m < 4; ++m) {
        int row = wr * 64 + m * 16 + l15;
        int pc = (kh * 4 + lg) ^ (row & 7);
        af[m] = *(const bf16x8*)((const char*)As + (row * 8 + pc) * 16);
      }
#pragma unroll
      for (int n = 0; n < 4; ++n) {
        int row = wc * 64 + n * 16 + l15;
        int pc = (kh * 4 + lg) ^ (row & 7);
        bf[n] = *(const bf16x8*)((const char*)Bs + (row * 8 + pc) * 16);
      }
#pragma unroll
      for (int m = 0; m < 4; ++m)
#pragma unroll
        for (int n = 0; n < 4; ++n)
          acc[m][n] = __builtin_amdgcn_mfma_f32_16x16x32_bf16(af[m], bf[n], acc[m][n], 0, 0, 0);
    }
    __syncthreads();
  }

  const int rbase = bm * 128 + wr * 64;
  const int cbase = bn * 128 + wc * 64;
#pragma unroll
  for (int m = 0; m < 4; ++m)
#pragma unroll
    for (int n = 0; n < 4; ++n)
#pragma unroll
      for (int r = 0; r < 4; ++r) {
        int row = rbase + m * 16 + lg * 4 + r;
        int col = cbase + n * 16 + l15;
        float v = acc[m][n][r];
        if (OUT_BF16)
          ((unsigned short*)Cv)[(size_t)row * N + col] = f2bf(v);
        else
          ((float*)Cv)[(size_t)row * N + col] = v;
      }
}

// ---- flash attention: qkv bf16 [B*T][3072] -> y bf16 [B*T][1024] ----
// grid (16 qtiles, B*H=128), 4 waves x 16 q-rows, KVBLK=64, dk=64
__global__ __launch_bounds__(256) void attn_fwd(const unsigned short* __restrict__ qkv,
                                                unsigned short* __restrict__ y) {
  const int qt = blockIdx.x;
  const int bh = blockIdx.y;
  const int b = bh >> 4, h = bh & 15;
  const int tid = threadIdx.x;
  const int wv = tid >> 6, lane = tid & 63;
  const int l15 = lane & 15, lg = lane >> 4;

  __shared__ unsigned short Ks[64 * 64];      // swizzled chunks
  __shared__ unsigned short Vs[64 * 64];      // linear row-major
  __shared__ unsigned short Ps[4][16][72];    // per-wave P transpose, padded

  const size_t base = (size_t)b * 1024 * 3072;
  const int q0 = qt * 64;
  const int qrow = q0 + wv * 16 + l15;

  bf16x8 qa[2];
#pragma unroll
  for (int kh = 0; kh < 2; ++kh)
    qa[kh] = *(const bf16x8*)(qkv + base + (size_t)qrow * 3072 + h * 64 + kh * 32 + lg * 8);

  float m_r[4], l_r[4];
#pragma unroll
  for (int r = 0; r < 4; ++r) { m_r[r] = -1e30f; l_r[r] = 0.f; }
  f32x4 oacc[4] = {};

  const int rowg_base = q0 + wv * 16 + lg * 4;
  const float LOG2E = 1.44269504089f;

  for (int t = 0; t <= qt; ++t) {
    const int kv0 = t * 64;
#pragma unroll
    for (int i = 0; i < 2; ++i) {
      int s = i * 256 + wv * 64 + lane;
      int row = s >> 3, pc = s & 7;
      int lc = pc ^ (row & 7);
      gload_lds16(qkv + base + (size_t)(kv0 + row) * 3072 + 1024 + h * 64 + lc * 8,
                  (char*)Ks + (size_t)(i * 256 + wv * 64) * 16);
      gload_lds16(qkv + base + (size_t)(kv0 + row) * 3072 + 2048 + h * 64 + pc * 8,
                  (char*)Vs + (size_t)(i * 256 + wv * 64) * 16);
    }
    __syncthreads();

    // S = Q K^T  (16 q-rows x 64 kv-cols per wave)
    f32x4 sacc[4] = {};
#pragma unroll
    for (int kh = 0; kh < 2; ++kh) {
      bf16x8 kf[4];
#pragma unroll
      for (int nt = 0; nt < 4; ++nt) {
        int row = nt * 16 + l15;
        int pc = (kh * 4 + lg) ^ (row & 7);
        kf[nt] = *(const bf16x8*)((const char*)Ks + (row * 8 + pc) * 16);
      }
#pragma unroll
      for (int nt = 0; nt < 4; ++nt)
        sacc[nt] = __builtin_amdgcn_mfma_f32_16x16x32_bf16(qa[kh], kf[nt], sacc[nt], 0, 0, 0);
    }

    const bool diag = (t == qt);
    float sv[4][4];  // [nt][r]
#pragma unroll
    for (int nt = 0; nt < 4; ++nt)
#pragma unroll
      for (int r = 0; r < 4; ++r) {
        float s = sacc[nt][r] * 0.125f;
        if (diag && (kv0 + nt * 16 + l15 > rowg_base + r)) s = -1e30f;
        sv[nt][r] = s;
      }

    // online softmax per q-row (16-lane group shares a row per reg r)
#pragma unroll
    for (int r = 0; r < 4; ++r) {
      float tm = fmaxf(fmaxf(sv[0][r], sv[1][r]), fmaxf(sv[2][r], sv[3][r]));
      tm = fmaxf(tm, __shfl_xor(tm, 1));
      tm = fmaxf(tm, __shfl_xor(tm, 2));
      tm = fmaxf(tm, __shfl_xor(tm, 4));
      tm = fmaxf(tm, __shfl_xor(tm, 8));
      float mnew = fmaxf(m_r[r], tm);
      float sc2 = exp2f((m_r[r] - mnew) * LOG2E);
      m_r[r] = mnew;
      float ps = 0.f;
#pragma unroll
      for (int nt = 0; nt < 4; ++nt) {
        float p = exp2f((sv[nt][r] - mnew) * LOG2E);
        sv[nt][r] = p;
        ps += p;
      }
      ps += __shfl_xor(ps, 1);
      ps += __shfl_xor(ps, 2);
      ps += __shfl_xor(ps, 4);
      ps += __shfl_xor(ps, 8);
      l_r[r] = l_r[r] * sc2 + ps;
#pragma unroll
      for (int nt = 0; nt < 4; ++nt) oacc[nt][r] *= sc2;
    }

    // transpose P through LDS (wave-local region)
#pragma unroll
    for (int nt = 0; nt < 4; ++nt)
#pragma unroll
      for (int r = 0; r < 4; ++r)
        Ps[wv][lg * 4 + r][nt * 16 + l15] = f2bf(sv[nt][r]);

    bf16x8 pa[2];
#pragma unroll
    for (int kh = 0; kh < 2; ++kh)
      pa[kh] = *(const bf16x8*)&Ps[wv][l15][kh * 32 + lg * 8];

    // O += P V
#pragma unroll
    for (int kh = 0; kh < 2; ++kh)
#pragma unroll
      for (int nt = 0; nt < 4; ++nt) {
        bf16x8 vf;
#pragma unroll
        for (int j = 0; j < 8; ++j)
          vf[j] = (short)Vs[(size_t)(kh * 32 + lg * 8 + j) * 64 + nt * 16 + l15];
        oacc[nt] = __builtin_amdgcn_mfma_f32_16x16x32_bf16(pa[kh], vf, oacc[nt], 0, 0, 0);
      }
    __syncthreads();
  }

#pragma unroll
  for (int nt = 0; nt < 4; ++nt)
#pragma unroll
    for (int r = 0; r < 4; ++r) {
      int row = rowg_base + r;
      int col = h * 64 + nt * 16 + l15;
      y[((size_t)b * 1024 + row) * 1024 + col] = f2bf(oacc[nt][r] / l_r[r]);
    }
}

extern "C" void kernel_launch(void* const* d_in, const int* in_sizes, int n_in,
                              void* d_out, int out_size, void* d_ws, size_t ws_size,
                              hipStream_t stream) {
  const float* x = (const float*)d_in[0];
  const float* w_qkv = (const float*)d_in[1];
  const float* w_proj = (const float*)d_in[2];

  // workspace layout (bytes):
  //   [0,16MB)   x_bf16, later reused as y_bf16
  //   [16,22MB)  w_qkv^T bf16 [3072][1024]
  //   [22,24MB)  w_proj^T bf16 [1024][1024]
  //   [24,72MB)  qkv bf16 [8192][3072]
  unsigned short* xb     = (unsigned short*)d_ws;
  unsigned short* wqkvT  = (unsigned short*)((char*)d_ws + (16u << 20));
  unsigned short* wprojT = (unsigned short*)((char*)d_ws + (22u << 20));
  unsigned short* qkvb   = (unsigned short*)((char*)d_ws + (24u << 20));

  cvt_f32_bf16<<<2048, 256, 0, stream>>>(x, xb, (8 * 1024 * 1024) / 4);
  tconv<<<dim3(96, 32), 256, 0, stream>>>(w_qkv, wqkvT, 1024, 3072);
  tconv<<<dim3(32, 32), 256, 0, stream>>>(w_proj, wprojT, 1024, 1024);

  gemm_bt<1><<<dim3(24, 64), 256, 0, stream>>>(xb, wqkvT, qkvb, 8192, 3072, 1024);

  attn_fwd<<<dim3(16, 128), 256, 0, stream>>>(qkvb, xb /* y */);

  gemm_bt<0><<<dim3(8, 64), 256, 0, stream>>>(xb, wprojT, d_out, 8192, 1024, 1024);
}

// Round 4
// 271.841 us; speedup vs baseline: 1.2405x; 1.2405x over previous
//
#include <hip/hip_runtime.h>

// ---- types ----
typedef short bf16x8 __attribute__((ext_vector_type(8)));
typedef float f32x4 __attribute__((ext_vector_type(4)));

__device__ __forceinline__ unsigned short f2bf(float f) {
  unsigned u = __builtin_bit_cast(unsigned, f);
  u += 0x7fff + ((u >> 16) & 1);   // RNE
  return (unsigned short)(u >> 16);
}

__device__ __forceinline__ void gload_lds16(const void* g, void* l) {
  __builtin_amdgcn_global_load_lds(
      (const __attribute__((address_space(1))) void*)g,
      (__attribute__((address_space(3))) void*)l, 16, 0, 0);
}

// ---- fp32 -> bf16 elementwise ----
__global__ __launch_bounds__(256) void cvt_f32_bf16(const float* __restrict__ in,
                                                    unsigned short* __restrict__ out,
                                                    int n4) {
  int i = blockIdx.x * blockDim.x + threadIdx.x;
  int stride = gridDim.x * blockDim.x;
  for (; i < n4; i += stride) {
    float4 v = ((const float4*)in)[i];
    ushort4 o;
    o.x = f2bf(v.x); o.y = f2bf(v.y); o.z = f2bf(v.z); o.w = f2bf(v.w);
    ((ushort4*)out)[i] = o;
  }
}

// ---- transpose + convert: in [R][C] f32 -> out [C][R] bf16 ----
__global__ __launch_bounds__(256) void tconv(const float* __restrict__ in,
                                             unsigned short* __restrict__ out,
                                             int R, int C) {
  __shared__ float tile[32][33];
  const int c0 = blockIdx.x * 32, r0 = blockIdx.y * 32;
  const int tid = threadIdx.x;
  const int tr = tid >> 3;
  const int tc4 = tid & 7;
  float4 v = *(const float4*)&in[(size_t)(r0 + tr) * C + c0 + tc4 * 4];
  tile[tr][tc4 * 4 + 0] = v.x;
  tile[tr][tc4 * 4 + 1] = v.y;
  tile[tr][tc4 * 4 + 2] = v.z;
  tile[tr][tc4 * 4 + 3] = v.w;
  __syncthreads();
#pragma unroll
  for (int i = 0; i < 4; ++i)
    out[(size_t)(c0 + tr) * R + r0 + tc4 * 4 + i] = f2bf(tile[tc4 * 4 + i][tr]);
}

// ---- V transpose within each (b,h): qkv [B*T][3072] V-cols -> vT [128 bh][64 d][1024 t] ----
__global__ __launch_bounds__(256) void transpV(const unsigned short* __restrict__ qkv,
                                               unsigned short* __restrict__ vT) {
  const int tt = blockIdx.x, bh = blockIdx.y;
  const int b = bh >> 4, h = bh & 15;
  __shared__ unsigned short tile[64 * 64];   // [t][d] linear
  const int tid = threadIdx.x;
  const size_t gbase = (size_t)b * 1024 * 3072 + 2048 + (size_t)h * 64;
#pragma unroll
  for (int i = 0; i < 2; ++i) {
    int c = i * 256 + tid;
    int trow = c >> 3, dc = c & 7;
    *(uint4*)(&tile[c * 8]) =
        *(const uint4*)(qkv + gbase + (size_t)(tt * 64 + trow) * 3072 + dc * 8);
  }
  __syncthreads();
  // read transposed: lane d spans 0..63 within a wave -> bank = d/2, conflict-free
  const int d = tid & 63, th = tid >> 6;
  unsigned short buf[16];
#pragma unroll
  for (int j = 0; j < 16; ++j) buf[j] = tile[(th * 16 + j) * 64 + d];
  size_t obase = ((size_t)bh * 64 + d) * 1024 + tt * 64 + th * 16;
  *(uint4*)(&vT[obase]) = *(uint4*)(&buf[0]);
  *(uint4*)(&vT[obase + 8]) = *(uint4*)(&buf[8]);
}

// ---- bf16 MFMA GEMM: C[M][N] = A[M][K](lda) * B^T[N][K] ----
template <int OUT_BF16>
__global__ __launch_bounds__(256) void gemm_bt(const unsigned short* __restrict__ A,
                                               const unsigned short* __restrict__ B,
                                               void* __restrict__ Cv,
                                               int M, int N, int K, int lda) {
  __shared__ unsigned short As[128 * 64];
  __shared__ unsigned short Bs[128 * 64];
  const int tid = threadIdx.x;
  const int wv = tid >> 6, lane = tid & 63;
  const int l15 = lane & 15, lg = lane >> 4;
  const int bm = blockIdx.y, bn = blockIdx.x;
  const int wr = wv >> 1, wc = wv & 1;
  f32x4 acc[4][4] = {};
  const unsigned short* Ab = A + (size_t)bm * 128 * lda;
  const unsigned short* Bb = B + (size_t)bn * 128 * K;

  for (int k0 = 0; k0 < K; k0 += 64) {
#pragma unroll
    for (int i = 0; i < 4; ++i) {
      int s = i * 256 + wv * 64 + lane;
      int row = s >> 3, pc = s & 7;
      int lc = pc ^ (row & 7);
      gload_lds16(Ab + (size_t)row * lda + k0 + lc * 8,
                  (char*)As + (size_t)(i * 256 + wv * 64) * 16);
      gload_lds16(Bb + (size_t)row * K + k0 + lc * 8,
                  (char*)Bs + (size_t)(i * 256 + wv * 64) * 16);
    }
    __syncthreads();
#pragma unroll
    for (int kh = 0; kh < 2; ++kh) {
      bf16x8 af[4], bf[4];
#pragma unroll
      for (int m = 0; m < 4; ++m) {
        int row = wr * 64 + m * 16 + l15;
        int pc = (kh * 4 + lg) ^ (row & 7);
        af[m] = *(const bf16x8*)((const char*)As + (row * 8 + pc) * 16);
      }
#pragma unroll
      for (int n = 0; n < 4; ++n) {
        int row = wc * 64 + n * 16 + l15;
        int pc = (kh * 4 + lg) ^ (row & 7);
        bf[n] = *(const bf16x8*)((const char*)Bs + (row * 8 + pc) * 16);
      }
#pragma unroll
      for (int m = 0; m < 4; ++m)
#pragma unroll
        for (int n = 0; n < 4; ++n)
          acc[m][n] = __builtin_amdgcn_mfma_f32_16x16x32_bf16(af[m], bf[n], acc[m][n], 0, 0, 0);
    }
    __syncthreads();
  }

  const int rbase = bm * 128 + wr * 64;
  const int cbase = bn * 128 + wc * 64;
#pragma unroll
  for (int m = 0; m < 4; ++m)
#pragma unroll
    for (int n = 0; n < 4; ++n)
#pragma unroll
      for (int r = 0; r < 4; ++r) {
        int row = rbase + m * 16 + lg * 4 + r;
        int col = cbase + n * 16 + l15;
        float v = acc[m][n][r];
        if (OUT_BF16)
          ((unsigned short*)Cv)[(size_t)row * N + col] = f2bf(v);
        else
          ((float*)Cv)[(size_t)row * N + col] = v;
      }
}

// ---- flash attention, balanced qt-pairs + double-buffered staging ----
// grid (8 pairs, 128 bh): block handles qtiles {pair, 15-pair} -> 17 tile-iters each.
// y written into qkv's (dead) V columns: qkv[row*3072 + 2048 + col]
__global__ __launch_bounds__(256) void attn_fwd(const unsigned short* __restrict__ qkv,
                                                const unsigned short* __restrict__ vT,
                                                unsigned short* __restrict__ qkv_y) {
  const int pair = blockIdx.x;
  const int bh = blockIdx.y;
  const int b = bh >> 4, h = bh & 15;
  const int tid = threadIdx.x;
  const int wv = tid >> 6, lane = tid & 63;
  const int l15 = lane & 15, lg = lane >> 4;

  __shared__ unsigned short Ks[2][64 * 64];
  __shared__ unsigned short Vs[2][64 * 64];
  __shared__ unsigned short Ps[4][16][72];

  const size_t base = (size_t)b * 1024 * 3072;
  const float LOG2E = 1.44269504089f;

#pragma unroll
  for (int phase = 0; phase < 2; ++phase) {
    const int qt = phase ? 15 - pair : pair;
    const int q0 = qt * 64;
    const int qrow = q0 + wv * 16 + l15;
    const int rowg_base = q0 + wv * 16 + lg * 4;

    bf16x8 qa[2];
#pragma unroll
    for (int kh = 0; kh < 2; ++kh)
      qa[kh] = *(const bf16x8*)(qkv + base + (size_t)qrow * 3072 + h * 64 + kh * 32 + lg * 8);

    float m_r[4], l_r[4];
#pragma unroll
    for (int r = 0; r < 4; ++r) { m_r[r] = -1e30f; l_r[r] = 0.f; }
    f32x4 oacc[4] = {};

    // prologue stage tile 0 into buf 0
#pragma unroll
    for (int i = 0; i < 2; ++i) {
      int s = i * 256 + wv * 64 + lane;
      int row = s >> 3, pc = s & 7;
      int lc = pc ^ (row & 7);
      gload_lds16(qkv + base + (size_t)row * 3072 + 1024 + h * 64 + lc * 8,
                  (char*)(&Ks[0][0]) + (size_t)s * 16);
      gload_lds16(vT + ((size_t)bh * 64 + row) * 1024 + lc * 8,
                  (char*)(&Vs[0][0]) + (size_t)s * 16);
    }
    __syncthreads();

    for (int t = 0; t <= qt; ++t) {
      const int cur = t & 1;
      // prefetch next tile into other buffer (overlaps with compute below)
      if (t < qt) {
        const int kv1 = (t + 1) * 64;
#pragma unroll
        for (int i = 0; i < 2; ++i) {
          int s = i * 256 + wv * 64 + lane;
          int row = s >> 3, pc = s & 7;
          int lc = pc ^ (row & 7);
          gload_lds16(qkv + base + (size_t)(kv1 + row) * 3072 + 1024 + h * 64 + lc * 8,
                      (char*)(&Ks[cur ^ 1][0]) + (size_t)s * 16);
          gload_lds16(vT + ((size_t)bh * 64 + row) * 1024 + kv1 + lc * 8,
                      (char*)(&Vs[cur ^ 1][0]) + (size_t)s * 16);
        }
      }

      const int kv0 = t * 64;
      // S = Q K^T
      f32x4 sacc[4] = {};
#pragma unroll
      for (int kh = 0; kh < 2; ++kh) {
        bf16x8 kf[4];
#pragma unroll
        for (int nt = 0; nt < 4; ++nt) {
          int row = nt * 16 + l15;
          int pc = (kh * 4 + lg) ^ (row & 7);
          kf[nt] = *(const bf16x8*)((const char*)(&Ks[cur][0]) + (row * 8 + pc) * 16);
        }
#pragma unroll
        for (int nt = 0; nt < 4; ++nt)
          sacc[nt] = __builtin_amdgcn_mfma_f32_16x16x32_bf16(qa[kh], kf[nt], sacc[nt], 0, 0, 0);
      }

      const bool diag = (t == qt);
      float sv[4][4];
#pragma unroll
      for (int nt = 0; nt < 4; ++nt)
#pragma unroll
        for (int r = 0; r < 4; ++r) {
          float s = sacc[nt][r] * 0.125f;
          if (diag && (kv0 + nt * 16 + l15 > rowg_base + r)) s = -1e30f;
          sv[nt][r] = s;
        }

#pragma unroll
      for (int r = 0; r < 4; ++r) {
        float tm = fmaxf(fmaxf(sv[0][r], sv[1][r]), fmaxf(sv[2][r], sv[3][r]));
        tm = fmaxf(tm, __shfl_xor(tm, 1));
        tm = fmaxf(tm, __shfl_xor(tm, 2));
        tm = fmaxf(tm, __shfl_xor(tm, 4));
        tm = fmaxf(tm, __shfl_xor(tm, 8));
        float mnew = fmaxf(m_r[r], tm);
        float sc2 = exp2f((m_r[r] - mnew) * LOG2E);
        m_r[r] = mnew;
        float ps = 0.f;
#pragma unroll
        for (int nt = 0; nt < 4; ++nt) {
          float p = exp2f((sv[nt][r] - mnew) * LOG2E);
          sv[nt][r] = p;
          ps += p;
        }
        ps += __shfl_xor(ps, 1);
        ps += __shfl_xor(ps, 2);
        ps += __shfl_xor(ps, 4);
        ps += __shfl_xor(ps, 8);
        l_r[r] = l_r[r] * sc2 + ps;
#pragma unroll
        for (int nt = 0; nt < 4; ++nt) oacc[nt][r] *= sc2;
      }

      // P transpose through wave-local LDS
#pragma unroll
      for (int nt = 0; nt < 4; ++nt)
#pragma unroll
        for (int r = 0; r < 4; ++r)
          Ps[wv][lg * 4 + r][nt * 16 + l15] = f2bf(sv[nt][r]);

      bf16x8 pa[2];
#pragma unroll
      for (int kh = 0; kh < 2; ++kh)
        pa[kh] = *(const bf16x8*)&Ps[wv][l15][kh * 32 + lg * 8];

      // O += P V  (V^T tile read with same swizzled b128 pattern as K)
#pragma unroll
      for (int kh = 0; kh < 2; ++kh)
#pragma unroll
        for (int nt = 0; nt < 4; ++nt) {
          int row = nt * 16 + l15;
          int pc = (kh * 4 + lg) ^ (row & 7);
          bf16x8 vf = *(const bf16x8*)((const char*)(&Vs[cur][0]) + (row * 8 + pc) * 16);
          oacc[nt] = __builtin_amdgcn_mfma_f32_16x16x32_bf16(pa[kh], vf, oacc[nt], 0, 0, 0);
        }
      __syncthreads();
    }

    // write y into qkv's V columns
#pragma unroll
    for (int nt = 0; nt < 4; ++nt)
#pragma unroll
      for (int r = 0; r < 4; ++r) {
        int row = rowg_base + r;
        int col = h * 64 + nt * 16 + l15;
        qkv_y[((size_t)b * 1024 + row) * 3072 + 2048 + col] = f2bf(oacc[nt][r] / l_r[r]);
      }
    __syncthreads();
  }
}

extern "C" void kernel_launch(void* const* d_in, const int* in_sizes, int n_in,
                              void* d_out, int out_size, void* d_ws, size_t ws_size,
                              hipStream_t stream) {
  const float* x = (const float*)d_in[0];
  const float* w_qkv = (const float*)d_in[1];
  const float* w_proj = (const float*)d_in[2];

  // workspace (72MB):
  //   [0,16MB)   x_bf16; reused as vT [128][64][1024] after gemm1
  //   [16,22MB)  w_qkv^T bf16
  //   [22,24MB)  w_proj^T bf16
  //   [24,72MB)  qkv bf16 [8192][3072]; V cols reused as y after transpV
  unsigned short* xb     = (unsigned short*)d_ws;
  unsigned short* vT     = (unsigned short*)d_ws;
  unsigned short* wqkvT  = (unsigned short*)((char*)d_ws + (16u << 20));
  unsigned short* wprojT = (unsigned short*)((char*)d_ws + (22u << 20));
  unsigned short* qkvb   = (unsigned short*)((char*)d_ws + (24u << 20));

  cvt_f32_bf16<<<2048, 256, 0, stream>>>(x, xb, (8 * 1024 * 1024) / 4);
  tconv<<<dim3(96, 32), 256, 0, stream>>>(w_qkv, wqkvT, 1024, 3072);
  tconv<<<dim3(32, 32), 256, 0, stream>>>(w_proj, wprojT, 1024, 1024);

  gemm_bt<1><<<dim3(24, 64), 256, 0, stream>>>(xb, wqkvT, qkvb, 8192, 3072, 1024, 1024);

  transpV<<<dim3(16, 128), 256, 0, stream>>>(qkvb, vT);

  attn_fwd<<<dim3(8, 128), 256, 0, stream>>>(qkvb, vT, qkvb);

  gemm_bt<0><<<dim3(8, 64), 256, 0, stream>>>(qkvb + 2048, wprojT, d_out, 8192, 1024, 1024, 3072);
}